// Round 3
// baseline (370.418 us; speedup 1.0000x reference)
//
#include <hip/hip_runtime.h>
#include <hip/hip_bf16.h>

typedef unsigned short u16;
typedef unsigned int u32;
typedef __attribute__((ext_vector_type(8))) short short8;
typedef __attribute__((ext_vector_type(4))) float f32x4;

#define DD 2048
constexpr int OFF_P2   = 512000;            // 250*2048
constexpr int OFF_CTX1 = 518750;            // +250*27
constexpr int OFF_P1   = 574046;            // +27*2048

// workspace layout (float offsets)
constexpr int Q1S = 0;                      // q1 [256][2048]
constexpr int K1S = 524288;                 // k1 [256][2048]
constexpr int V1S = 1048576;                // v1 [256][2048]
constexpr int SMP = 1572864;                // 12 x [32][2048] small partials (q2 p0-3, k2 p0-3, v2 p0-3)
constexpr int S1P = 2359296;                // [8][32*256]
constexpr int S2P = 2424832;                // [8][32*256]
constexpr int G1A = 2490368;                // [32]

__device__ __forceinline__ u32 pk2(float a, float b){
  __hip_bfloat162 h = __float22bfloat162_rn(make_float2(a, b));
  u32 r; __builtin_memcpy(&r, &h, 4); return r;
}
__device__ __forceinline__ short8 cvt8(float4 u, float4 v, bool ok){
  union { short8 s; u32 w[4]; } r;
  r.w[0] = ok ? pk2(u.x,u.y) : 0u;
  r.w[1] = ok ? pk2(u.z,u.w) : 0u;
  r.w[2] = ok ? pk2(v.x,v.y) : 0u;
  r.w[3] = ok ? pk2(v.z,v.w) : 0u;
  return r.s;
}

// ---------------------------------------------------------------------------
// Register-streaming NT GEMM: C[m,n] = sum_k A[m,k]*B[n,k]  (both row-major,
// fp32 in global, converted to bf16 in registers, MFMA 16x16x32, no LDS,
// no barriers, 2-deep K-step prefetch). A may be a sum of NP partial slices
// (stride Aslice floats apart).
// ---------------------------------------------------------------------------
template<int MF, int NF, int KST, int NP>
__device__ __forceinline__ void gemm_reg(
    const float* __restrict__ A, int Aslice,
    int mbase, int Mclamp,
    const float* __restrict__ W, int nbase, int kbase,
    const float* __restrict__ bias, bool addb,
    float* __restrict__ outp, int ldo, int obase_m, int obase_n, int lane)
{
  const int lr = lane & 15, lk8 = (lane >> 4) * 8;
  const float* ap[MF]; bool aok[MF];
#pragma unroll
  for (int mf=0; mf<MF; ++mf){
    int gm = mbase + mf*16 + lr;
    aok[mf] = gm < Mclamp;
    int cg = aok[mf] ? gm : (Mclamp-1);
    ap[mf] = A + (size_t)cg*DD + kbase + lk8;
  }
  const float* bp[NF];
#pragma unroll
  for (int nf=0; nf<NF; ++nf)
    bp[nf] = W + (size_t)(nbase + nf*16 + lr)*DD + kbase + lk8;

  f32x4 acc[MF][NF];
#pragma unroll
  for (int i=0;i<MF;i++)
#pragma unroll
    for (int j=0;j<NF;j++) acc[i][j] = (f32x4){0.f,0.f,0.f,0.f};

  float4 ax[MF][NP][2], bx[NF][2];
  float4 ay[MF][NP][2], by[NF][2];

  auto issue = [&](int ks, float4 (&am)[MF][NP][2], float4 (&bm)[NF][2]){
    const int off = ks*32;
#pragma unroll
    for (int mf=0; mf<MF; ++mf)
#pragma unroll
      for (int p=0; p<NP; ++p){
        am[mf][p][0] = *(const float4*)(ap[mf] + (size_t)p*Aslice + off);
        am[mf][p][1] = *(const float4*)(ap[mf] + (size_t)p*Aslice + off + 4);
      }
#pragma unroll
    for (int nf=0; nf<NF; ++nf){
      bm[nf][0] = *(const float4*)(bp[nf] + off);
      bm[nf][1] = *(const float4*)(bp[nf] + off + 4);
    }
  };
  auto comp = [&](float4 (&am)[MF][NP][2], float4 (&bm)[NF][2]){
    short8 af[MF], bf[NF];
#pragma unroll
    for (int mf=0; mf<MF; ++mf){
      float4 u = am[mf][0][0], v = am[mf][0][1];
#pragma unroll
      for (int p=1; p<NP; ++p){ u += am[mf][p][0]; v += am[mf][p][1]; }
      af[mf] = cvt8(u, v, aok[mf]);
    }
#pragma unroll
    for (int nf=0; nf<NF; ++nf) bf[nf] = cvt8(bm[nf][0], bm[nf][1], true);
#pragma unroll
    for (int mf=0; mf<MF; ++mf)
#pragma unroll
      for (int nf=0; nf<NF; ++nf)
        acc[mf][nf] = __builtin_amdgcn_mfma_f32_16x16x32_bf16(af[mf], bf[nf], acc[mf][nf], 0,0,0);
  };

  issue(0, ax, bx);
#pragma unroll 1
  for (int ks=0; ks<KST; ks+=2){
    issue(ks+1, ay, by);
    comp(ax, bx);
    issue(ks+2 < KST ? ks+2 : 0, ax, bx);
    comp(ay, by);
  }

  const int lq = (lane>>4)*4;
#pragma unroll
  for (int mf=0; mf<MF; ++mf)
#pragma unroll
    for (int nf=0; nf<NF; ++nf){
      int col = obase_n + nf*16 + lr;
      float bv = addb ? bias[col] : 0.f;
#pragma unroll
      for (int rr=0; rr<4; ++rr){
        int row = obase_m + mf*16 + lq + rr;
        outp[(size_t)row*ldo + col] = acc[mf][nf][rr] + bv;
      }
    }
}

struct P6 { const float* W[6]; const float* b[6]; };

// ---------------------------------------------------------------------------
// kA: all six projections.
//   blocks 0..191:  q1/k1/v1 = in1 @ W^T + b  (full K, single writer)
//                   mat = b/64; 2 mtiles(128) x 32 ntiles(64); wave = 64m x 32n
//   blocks 192..287: q2/k2/v2 partials (K-split 4)
//                   mat = s/32; 8 ntiles(256) x 4 ks; wave = 32m x 64n
// ---------------------------------------------------------------------------
__global__ __launch_bounds__(256) void kA(const float* __restrict__ in1,
                                          const float* __restrict__ in2,
                                          P6 par, float* __restrict__ ws)
{
  const int b = blockIdx.x, t = threadIdx.x, l = t&63, w = t>>6;
  if (b < 192){
    const int mat = b>>6, r = b&63, mt = r>>5, nt = r&31;
    const int wm = w>>1, wn = w&1;
    const int mbase = mt*128 + wm*64, nbase = nt*64 + wn*32;
    gemm_reg<4,2,64,1>(in1, 0, mbase, 250, par.W[mat], nbase, 0,
                       par.b[mat], true, ws + (size_t)mat*524288, DD, mbase, nbase, l);
  } else {
    const int s = b - 192, mat = s>>5, r = s&31, nt = r>>2, ksp = r&3;
    const int nbase = nt*256 + w*64;
    gemm_reg<2,4,16,1>(in2, 0, 0, 27, par.W[3+mat], nbase, ksp*512,
                       par.b[3+mat], ksp==0,
                       ws + SMP + (size_t)(mat*4+ksp)*65536, DD, 0, nbase, l);
  }
}

// ---------------------------------------------------------------------------
// kS: S1 = q2 @ k1^T, S2^T = k2 @ q1^T (K-split 8 partials to ws).
//     A-side sums the 4 projection partials inline. Also zeroes g1acc.
//     32 blocks: mat(2) x jt(2 of 128) x ks(8); wave = 32t x 32j.
// ---------------------------------------------------------------------------
__global__ __launch_bounds__(256) void kS(float* __restrict__ ws)
{
  const int b = blockIdx.x, t = threadIdx.x, l = t&63, w = t>>6;
  if (b == 0 && t < 32) ws[G1A + t] = 0.f;
  const int mat = b>>4, r = b&15, jt = r>>3, ksp = r&7;
  const float* Ab = ws + SMP + (size_t)mat*4*65536;     // q2 or k2 partials
  const float* Bb = ws + (mat ? Q1S : K1S);             // q1 or k1
  float* OUT = ws + (mat ? S2P : S1P) + ksp*8192;
  const int jbase = jt*128 + w*32;
  gemm_reg<2,2,8,4>(Ab, 65536, 0, 32, Bb, jbase, ksp*256,
                    nullptr, false, OUT, 256, 0, jbase, l);
}

// ---------------------------------------------------------------------------
// k_finish: per j-row (250 blocks): sum S partials -> sigmoid -> probs1/probs2,
//   g1 atomics, g2 wave-reduce, ctx2 row = v1[j]*g2 + b_fc2.
// ---------------------------------------------------------------------------
__global__ __launch_bounds__(256) void k_finish(
    const float* __restrict__ ws,
    const float* __restrict__ w_fc1, const float* __restrict__ w_fc2,
    const float* __restrict__ b_fc1p, const float* __restrict__ b_fc2p,
    float* __restrict__ g1acc, float* __restrict__ d_out)
{
  const int j = blockIdx.x, t = threadIdx.x, l = t&63, w = t>>6;
  __shared__ float g2s;
  if (w == 0){
    const float scale = 0.022097086912079608f;   // 1/sqrt(2048)
    float gv = 0.f;
    if (l < 27){
      const float* S1p = ws + S1P;
      const float* S2p = ws + S2P;
      float s1 = 0.f, s2 = 0.f;
#pragma unroll
      for (int p=0;p<8;p++){
        s1 += S1p[p*8192 + l*256 + j];
        s2 += S2p[p*8192 + l*256 + j];
      }
      float p1 = 1.f / (1.f + expf(-s1*scale));
      float p2 = 1.f / (1.f + expf(-s2*scale));
      d_out[OFF_P1 + l*250 + j] = p1;
      d_out[OFF_P2 + j*27 + l] = p2;
      atomicAdd(&g1acc[l], p1 * w_fc1[j]);
      gv = p2 * w_fc2[l];
    }
#pragma unroll
    for (int off=32; off; off>>=1) gv += __shfl_xor(gv, off);
    if (l == 0) g2s = gv;
  }
  __syncthreads();
  const float g2 = g2s, bfc2 = b_fc2p[0];
  const float* v1 = ws + V1S + (size_t)j*DD;
#pragma unroll
  for (int i=0;i<2;i++){
    int e = (t + 256*i)*4;
    float4 v = *(const float4*)&v1[e];
    float4 o;
    o.x = v.x*g2 + bfc2; o.y = v.y*g2 + bfc2;
    o.z = v.z*g2 + bfc2; o.w = v.w*g2 + bfc2;
    *(float4*)&d_out[(size_t)j*DD + e] = o;
  }
}

// ---------------------------------------------------------------------------
// k_ctx1: ctx1 = (sum of 4 v2 partials) * g1[row] + b_fc1
// ---------------------------------------------------------------------------
__global__ __launch_bounds__(256) void k_ctx1(
    const float* __restrict__ ws, const float* __restrict__ b_fc1p,
    float* __restrict__ d_out)
{
  const int i = blockIdx.x*256 + threadIdx.x;   // float4 index
  if (i >= 27*512) return;
  const int row = i >> 9, c4 = (i & 511)*4;
  const float* v2 = ws + SMP + (size_t)8*65536 + (size_t)row*DD + c4;
  float4 v0 = *(const float4*)(v2);
  float4 v1 = *(const float4*)(v2 + 65536);
  float4 v2b = *(const float4*)(v2 + 2*65536);
  float4 v3 = *(const float4*)(v2 + 3*65536);
  const float g = ws[G1A + row], bb = b_fc1p[0];
  float4 o;
  o.x = ((v0.x+v1.x)+(v2b.x+v3.x))*g + bb;
  o.y = ((v0.y+v1.y)+(v2b.y+v3.y))*g + bb;
  o.z = ((v0.z+v1.z)+(v2b.z+v3.z))*g + bb;
  o.w = ((v0.w+v1.w)+(v2b.w+v3.w))*g + bb;
  *(float4*)&d_out[OFF_CTX1 + (size_t)row*DD + c4] = o;
}

// ---------------------------------------------------------------------------
extern "C" void kernel_launch(void* const* d_in, const int* in_sizes, int n_in,
                              void* d_out, int out_size, void* d_ws, size_t ws_size,
                              hipStream_t stream)
{
  const float* in1 = (const float*)d_in[0];
  const float* in2 = (const float*)d_in[1];
  P6 par;
  par.W[0] = (const float*)d_in[2];  par.b[0] = (const float*)d_in[3];   // Wq1
  par.W[1] = (const float*)d_in[4];  par.b[1] = (const float*)d_in[5];   // Wk1
  par.W[2] = (const float*)d_in[6];  par.b[2] = (const float*)d_in[7];   // Wv1
  par.W[3] = (const float*)d_in[8];  par.b[3] = (const float*)d_in[9];   // Wq2
  par.W[4] = (const float*)d_in[10]; par.b[4] = (const float*)d_in[11];  // Wk2
  par.W[5] = (const float*)d_in[12]; par.b[5] = (const float*)d_in[13];  // Wv2
  const float* wfc1 = (const float*)d_in[14]; const float* bfc1 = (const float*)d_in[15];
  const float* wfc2 = (const float*)d_in[16]; const float* bfc2 = (const float*)d_in[17];
  float* out = (float*)d_out;
  float* ws  = (float*)d_ws;

  kA<<<288, 256, 0, stream>>>(in1, in2, par, ws);
  kS<<<32, 256, 0, stream>>>(ws);
  k_finish<<<250, 256, 0, stream>>>(ws, wfc1, wfc2, bfc1, bfc2, ws + G1A, out);
  k_ctx1<<<54, 256, 0, stream>>>(ws, bfc1, out);
}

// Round 5
// 307.554 us; speedup vs baseline: 1.2044x; 1.2044x over previous
//
#include <hip/hip_runtime.h>
#include <hip/hip_bf16.h>

typedef unsigned short u16;
typedef unsigned int u32;
typedef __attribute__((ext_vector_type(8))) short short8;
typedef __attribute__((ext_vector_type(4))) float f32x4;

#define DD 2048
constexpr int OFF_P2   = 512000;            // 250*2048
constexpr int OFF_CTX1 = 518750;            // +250*27
constexpr int OFF_P1   = 574046;            // +27*2048

// ---- workspace layout (BYTE offsets) ----
constexpr size_t A1TL = 0;                                   // 1024 tiles x 1KB = 1MB (in1 frag-major bf16)
constexpr size_t A2TL = A1TL + (size_t)1024*1024;            // 128 tiles = 128KB (in2)
constexpr size_t PB   = A2TL + (size_t)128*1024;             // big partials: 12 x [256][2048] bf16 = 12MB
constexpr size_t PS   = PB + (size_t)12*256*DD*2;            // small partials: 12 x [32][2048] bf16 = 1.5MB
constexpr size_t S1P  = PS + (size_t)12*32*DD*2;             // 32 x [32*256] f32 = 1MB
constexpr size_t S2P  = S1P + (size_t)32*8192*4;             // 1MB
constexpr size_t G1A  = S2P + (size_t)32*8192*4;             // 32 f32

__device__ __forceinline__ u16 f2bf(float f){
  u32 u = __float_as_uint(f);
  u += 0x7fffu + ((u >> 16) & 1u);
  return (u16)(u >> 16);
}
__device__ __forceinline__ u32 pk2(float a, float b){
  __hip_bfloat162 h = __float22bfloat162_rn(make_float2(a, b));
  u32 r; __builtin_memcpy(&r, &h, 4); return r;
}
__device__ __forceinline__ float bflo(u32 u){ return __uint_as_float(u << 16); }
__device__ __forceinline__ float bfhi(u32 u){ return __uint_as_float(u & 0xffff0000u); }

__device__ __forceinline__ void gload_lds16(const float* g, float* l){
  __builtin_amdgcn_global_load_lds((const __attribute__((address_space(1))) unsigned*)g,
                                   (__attribute__((address_space(3))) unsigned*)l, 16, 0, 0);
}

union U4 { uint4 v; u32 u[4]; };
union S8U { short8 s; u32 u[4]; uint4 v; };

struct P6 { const float* W[6]; const float* b[6]; };

// ---------------------------------------------------------------------------
// kPre: build fragment-major bf16 tiles of in1/in2 (A-operand layout for
// mfma 16x16x32: lane l holds rows mb*16+(l&15), k = kb*32+(l>>4)*8 .. +7,
// stored as tile[(mb*64+kb)*1024B + l*16B]).  Also zeroes g1acc.
// ---------------------------------------------------------------------------
__global__ __launch_bounds__(256) void kPre(const float* __restrict__ in1,
                                            const float* __restrict__ in2,
                                            char* __restrict__ wsb)
{
  const int gid = blockIdx.x*256 + threadIdx.x;
  if (gid < 32) ((float*)(wsb + G1A))[gid] = 0.f;
  const int tile = gid >> 6, l = gid & 63;
  const float* src; int Mreal, tl; size_t dstb;
  if (tile < 1024){ src = in1; Mreal = 250; tl = tile; dstb = A1TL; }
  else            { src = in2; Mreal = 27;  tl = tile - 1024; dstb = A2TL; }
  const int mb = tl >> 6, kb = tl & 63;
  const int m = mb*16 + (l & 15), k = kb*32 + (l >> 4)*8;
  u32 r0=0, r1=0, r2=0, r3=0;
  if (m < Mreal){
    const float* p = src + (size_t)m*DD + k;
    float4 a = *(const float4*)p;
    float4 b = *(const float4*)(p + 4);
    r0 = pk2(a.x,a.y); r1 = pk2(a.z,a.w); r2 = pk2(b.x,b.y); r3 = pk2(b.z,b.w);
  }
  *(uint4*)(wsb + dstb + (size_t)tl*1024 + (size_t)l*16) = make_uint4(r0,r1,r2,r3);
}

// ---------------------------------------------------------------------------
// GEMM worker: C[m,n] partial (K-chunk 512, 16 steps of BK=32) of A @ W^T.
//  - W staged fp32 via global_load_lds into XOR-swizzled LDS (16B pieces:
//    store pos ps holds global piece ps^(row&7); read applies same XOR)
//  - A-fragments from pre-tiled bf16 (wave-contiguous 1KB loads)
//  - T3-minimal pipeline: stage(next) issued before compute, 1 barrier/step
// ---------------------------------------------------------------------------
template<int MF, int NF, int STG>
__device__ __forceinline__ void worker(
    const float* __restrict__ Wn, int kc0,
    const float* __restrict__ bias, bool addb,
    const u16* __restrict__ Atlb, int mb0, int brow0,
    u16* __restrict__ outp, int orow0, int ocol0,
    float (*lds)[2048], int t)
{
  const int l = t & 63, w = t >> 6, lr = l & 15, lk = l >> 4;

  auto stage = [&](int buf, int kc){
#pragma unroll
    for (int c = 0; c < STG; ++c){
      int pi = c*256 + t;
      int row = pi >> 3, ps = pi & 7, psrc = ps ^ (row & 7);
      gload_lds16(Wn + (size_t)row*DD + kc + psrc*4, &lds[buf][(c*256 + w*64)*4]);
    }
  };
  uint4 Aa[MF], Ab[MF];
  auto loadA = [&](int kb, uint4* dst){
#pragma unroll
    for (int mf = 0; mf < MF; ++mf)
      dst[mf] = *(const uint4*)(Atlb + ((size_t)(mb0+mf)*64 + kb)*512 + (size_t)l*8);
  };

  f32x4 acc[MF][NF];
#pragma unroll
  for (int i=0;i<MF;i++)
#pragma unroll
    for (int j=0;j<NF;j++) acc[i][j] = (f32x4){0.f,0.f,0.f,0.f};

  const int kb0 = kc0 >> 5;
  stage(0, kc0);
  loadA(kb0, Aa);
  __syncthreads();

  int cur = 0;
#pragma unroll 1
  for (int s = 0; s < 16; ++s){
    if (s < 15){
      stage(cur ^ 1, kc0 + (s+1)*32);
      loadA(kb0 + s + 1, (s & 1) ? Aa : Ab);
    }
    short8 bf[NF];
#pragma unroll
    for (int nf = 0; nf < NF; ++nf){
      int rrow = brow0 + nf*16 + lr;
      int p0 = (lk*2) ^ (rrow & 7), p1 = (lk*2+1) ^ (rrow & 7);
      const float* base = &lds[cur][rrow*32];
      float4 f0 = *(const float4*)(base + p0*4);
      float4 f1 = *(const float4*)(base + p1*4);
      S8U q;
      q.u[0] = pk2(f0.x,f0.y); q.u[1] = pk2(f0.z,f0.w);
      q.u[2] = pk2(f1.x,f1.y); q.u[3] = pk2(f1.z,f1.w);
      bf[nf] = q.s;
    }
#pragma unroll
    for (int mf = 0; mf < MF; ++mf){
      S8U a; a.v = (s & 1) ? Ab[mf] : Aa[mf];
#pragma unroll
      for (int nf = 0; nf < NF; ++nf)
        acc[mf][nf] = __builtin_amdgcn_mfma_f32_16x16x32_bf16(a.s, bf[nf], acc[mf][nf], 0,0,0);
    }
    __syncthreads();
    cur ^= 1;
  }

  const int lq = lk*4;
#pragma unroll
  for (int mf = 0; mf < MF; ++mf)
#pragma unroll
    for (int nf = 0; nf < NF; ++nf){
      int col = ocol0 + nf*16 + lr;
      float bv = addb ? bias[col] : 0.f;
#pragma unroll
      for (int rr = 0; rr < 4; ++rr){
        int row = orow0 + mf*16 + lq + rr;
        outp[(size_t)row*DD + col] = f2bf(acc[mf][nf][rr] + bv);
      }
    }
}

// ---------------------------------------------------------------------------
// kW: all six projections as bf16 K-split partials.
//  blocks [0,768):   big mats q1/k1/v1: [256m x 32n] x ks4; wave w: m 64w..64w+63
//  blocks [768,1152): small mats q2/k2/v2: [32m x 64n] x ks4; wave w: n-sub 16w
// ---------------------------------------------------------------------------
__global__ __launch_bounds__(256) void kW(P6 par, char* __restrict__ wsb)
{
  __shared__ float lds[2][2048];    // 16 KiB
  const int b = blockIdx.x, t = threadIdx.x, w = t >> 6;
  if (b < 768){
    const int g = b >> 8, r = b & 255, nt = r >> 2, ks = r & 3;
    const float* Wn = par.W[g] + (size_t)nt*32*DD;
    u16* outp = (u16*)(wsb + PB) + (size_t)(g*4 + ks)*256*DD;
    worker<4,2,1>(Wn, ks*512, par.b[g], ks==0,
                  (const u16*)(wsb + A1TL), w*4, 0,
                  outp, w*64, nt*32, lds, t);
  } else {
    const int s = b - 768, g = s >> 7, r = s & 127, nt = r >> 2, ks = r & 3;
    const float* Wn = par.W[3+g] + (size_t)nt*64*DD;
    u16* outp = (u16*)(wsb + PS) + (size_t)(g*4 + ks)*32*DD;
    worker<2,1,2>(Wn, ks*512, par.b[3+g], ks==0,
                  (const u16*)(wsb + A2TL), 0, w*16,
                  outp, 0, nt*64 + w*16, lds, t);
  }
}

// ---------------------------------------------------------------------------
// kS: S1 = q2 @ k1^T, S2^T = k2 @ q1^T (fp32 partial copies, 32 per mat).
//  64 blocks: mat(2) x jt(4 of 64) x kc(8 of 256); wave w: k-sub 64.
//  Operands = sum of 4 bf16 partial copies (summed in f32, repacked).
// ---------------------------------------------------------------------------
__device__ __forceinline__ short8 sum4bf(const u16* p, size_t stride){
  U4 a,b,c,d;
  a.v = *(const uint4*)p;
  b.v = *(const uint4*)(p + stride);
  c.v = *(const uint4*)(p + 2*stride);
  d.v = *(const uint4*)(p + 3*stride);
  S8U o;
#pragma unroll
  for (int q=0;q<4;q++){
    float e0 = (bflo(a.u[q])+bflo(b.u[q])) + (bflo(c.u[q])+bflo(d.u[q]));
    float e1 = (bfhi(a.u[q])+bfhi(b.u[q])) + (bfhi(c.u[q])+bfhi(d.u[q]));
    o.u[q] = pk2(e0, e1);
  }
  return o.s;
}

__global__ __launch_bounds__(256) void kS(char* __restrict__ wsb)
{
  const int b = blockIdx.x, t = threadIdx.x, l = t & 63, w = t >> 6;
  const int lr = l & 15, lk = l >> 4;
  const int mat = b >> 5, r = b & 31, jt = r >> 3, kc = r & 7;
  const u16* As = (const u16*)(wsb + PS) + (size_t)mat*4*32*DD;            // q2 / k2 copies
  const u16* Bs = (const u16*)(wsb + PB) + (size_t)(mat ? 0 : 1)*4*256*DD; // q1 / k1 copies
  float* OUT = (float*)(wsb + (mat ? S2P : S1P)) + (size_t)(kc*4 + w)*8192;
  const int k0 = kc*256 + w*64;

  f32x4 acc[2][4];
#pragma unroll
  for (int i=0;i<2;i++)
#pragma unroll
    for (int j=0;j<4;j++) acc[i][j] = (f32x4){0.f,0.f,0.f,0.f};

#pragma unroll
  for (int st = 0; st < 2; ++st){
    const int kk = k0 + st*32 + lk*8;
    short8 af[2];
#pragma unroll
    for (int mf=0; mf<2; ++mf)
      af[mf] = sum4bf(As + (size_t)(mf*16 + lr)*DD + kk, (size_t)32*DD);
#pragma unroll
    for (int nf=0; nf<4; ++nf){
      int j = jt*64 + nf*16 + lr;
      short8 bfr = sum4bf(Bs + (size_t)j*DD + kk, (size_t)256*DD);
#pragma unroll
      for (int mf=0; mf<2; ++mf)
        acc[mf][nf] = __builtin_amdgcn_mfma_f32_16x16x32_bf16(af[mf], bfr, acc[mf][nf], 0,0,0);
    }
  }
  const int lq = lk*4;
#pragma unroll
  for (int mf=0; mf<2; ++mf)
#pragma unroll
    for (int nf=0; nf<4; ++nf){
      int col = jt*64 + nf*16 + lr;
#pragma unroll
      for (int rr=0; rr<4; ++rr){
        int row = mf*16 + lq + rr;
        OUT[row*256 + col] = acc[mf][nf][rr];
      }
    }
}

// ---------------------------------------------------------------------------
// k_finish: per j (250 blocks): sum 32 S-copies -> sigmoid -> probs writes,
//  g1 atomics, g2 wave-reduce; ctx2 row = (sum 4 v1 copies)*g2 + b_fc2.
// ---------------------------------------------------------------------------
__global__ __launch_bounds__(256) void k_finish(
    const char* __restrict__ wsb,
    const float* __restrict__ w_fc1, const float* __restrict__ w_fc2,
    const float* __restrict__ b_fc1p, const float* __restrict__ b_fc2p,
    float* __restrict__ g1acc, float* __restrict__ d_out)
{
  const int j = blockIdx.x, t = threadIdx.x, w = t >> 6, l = t & 63;
  __shared__ float g2s;
  if (w == 0){
    const float scale = 0.022097086912079608f;   // 1/sqrt(2048)
    float gv = 0.f;
    if (l < 27){
      const float* S1p = (const float*)(wsb + S1P);
      const float* S2p = (const float*)(wsb + S2P);
      float s1 = 0.f, s2 = 0.f;
#pragma unroll
      for (int p=0;p<32;p++){
        s1 += S1p[p*8192 + l*256 + j];
        s2 += S2p[p*8192 + l*256 + j];
      }
      float p1 = 1.f / (1.f + expf(-s1*scale));
      float p2 = 1.f / (1.f + expf(-s2*scale));
      d_out[OFF_P1 + l*250 + j] = p1;
      d_out[OFF_P2 + j*27 + l] = p2;
      atomicAdd(&g1acc[l], p1 * w_fc1[j]);
      gv = p2 * w_fc2[l];
    }
#pragma unroll
    for (int off=32; off; off>>=1) gv += __shfl_xor(gv, off);
    if (l == 0) g2s = gv;
  }
  __syncthreads();
  const float g2 = g2s, bfc2 = b_fc2p[0];
  const u16* vp = (const u16*)(wsb + PB) + (size_t)8*256*DD + (size_t)j*DD + t*8;
  const size_t cs = (size_t)256*DD;
  U4 a,b,c,d;
  a.v = *(const uint4*)vp; b.v = *(const uint4*)(vp + cs);
  c.v = *(const uint4*)(vp + 2*cs); d.v = *(const uint4*)(vp + 3*cs);
  float o[8];
#pragma unroll
  for (int q=0;q<4;q++){
    o[2*q]   = ((bflo(a.u[q])+bflo(b.u[q])) + (bflo(c.u[q])+bflo(d.u[q])))*g2 + bfc2;
    o[2*q+1] = ((bfhi(a.u[q])+bfhi(b.u[q])) + (bfhi(c.u[q])+bfhi(d.u[q])))*g2 + bfc2;
  }
  float* op = &d_out[(size_t)j*DD + t*8];
  *(float4*)op = make_float4(o[0],o[1],o[2],o[3]);
  *(float4*)(op+4) = make_float4(o[4],o[5],o[6],o[7]);
}

// ---------------------------------------------------------------------------
// k_ctx1: row per block (27): ctx1 = (sum 4 v2 copies)*g1[row] + b_fc1
// ---------------------------------------------------------------------------
__global__ __launch_bounds__(256) void k_ctx1(
    const char* __restrict__ wsb, const float* __restrict__ b_fc1p,
    float* __restrict__ d_out)
{
  const int row = blockIdx.x, t = threadIdx.x;
  const u16* vp = (const u16*)(wsb + PS) + (size_t)8*32*DD + (size_t)row*DD + t*8;
  const size_t cs = (size_t)32*DD;
  const float g = ((const float*)(wsb + G1A))[row], bb = b_fc1p[0];
  U4 a,b,c,d;
  a.v = *(const uint4*)vp; b.v = *(const uint4*)(vp + cs);
  c.v = *(const uint4*)(vp + 2*cs); d.v = *(const uint4*)(vp + 3*cs);
  float o[8];
#pragma unroll
  for (int q=0;q<4;q++){
    o[2*q]   = ((bflo(a.u[q])+bflo(b.u[q])) + (bflo(c.u[q])+bflo(d.u[q])))*g + bb;
    o[2*q+1] = ((bfhi(a.u[q])+bfhi(b.u[q])) + (bfhi(c.u[q])+bfhi(d.u[q])))*g + bb;
  }
  float* op = &d_out[OFF_CTX1 + (size_t)row*DD + t*8];
  *(float4*)op = make_float4(o[0],o[1],o[2],o[3]);
  *(float4*)(op+4) = make_float4(o[4],o[5],o[6],o[7]);
}

// ---------------------------------------------------------------------------
extern "C" void kernel_launch(void* const* d_in, const int* in_sizes, int n_in,
                              void* d_out, int out_size, void* d_ws, size_t ws_size,
                              hipStream_t stream)
{
  const float* in1 = (const float*)d_in[0];
  const float* in2 = (const float*)d_in[1];
  P6 par;
  par.W[0] = (const float*)d_in[2];  par.b[0] = (const float*)d_in[3];   // Wq1
  par.W[1] = (const float*)d_in[4];  par.b[1] = (const float*)d_in[5];   // Wk1
  par.W[2] = (const float*)d_in[6];  par.b[2] = (const float*)d_in[7];   // Wv1
  par.W[3] = (const float*)d_in[8];  par.b[3] = (const float*)d_in[9];   // Wq2
  par.W[4] = (const float*)d_in[10]; par.b[4] = (const float*)d_in[11];  // Wk2
  par.W[5] = (const float*)d_in[12]; par.b[5] = (const float*)d_in[13];  // Wv2
  const float* wfc1 = (const float*)d_in[14]; const float* bfc1 = (const float*)d_in[15];
  const float* wfc2 = (const float*)d_in[16]; const float* bfc2 = (const float*)d_in[17];
  float* out = (float*)d_out;
  char* wsb  = (char*)d_ws;
  float* g1acc = (float*)(wsb + G1A);

  kPre<<<288, 256, 0, stream>>>(in1, in2, wsb);
  kW<<<1152, 256, 0, stream>>>(par, wsb);
  kS<<<64, 256, 0, stream>>>(wsb);
  k_finish<<<250, 256, 0, stream>>>(wsb, wfc1, wfc2, bfc1, bfc2, g1acc, out);
  k_ctx1<<<27, 256, 0, stream>>>(wsb, bfc1, out);
}